// Round 1
// baseline (1708.041 us; speedup 1.0000x reference)
//
#include <hip/hip_runtime.h>

#define THREADS 256

// ---------------- degree ----------------
__global__ void k_deg_init(float* __restrict__ deg, int n) {
    int i = blockIdx.x * blockDim.x + threadIdx.x;
    if (i < n) deg[i] = 1.0f;  // self-loop
}

__global__ void k_deg_acc(const int* __restrict__ dst, float* __restrict__ deg, int e) {
    int i = blockIdx.x * blockDim.x + threadIdx.x;
    if (i < e) atomicAdd(&deg[dst[i]], 1.0f);
}

__global__ void k_rsqrt(float* __restrict__ deg, int n) {
    int i = blockIdx.x * blockDim.x + threadIdx.x;
    if (i < n) deg[i] = rsqrtf(deg[i]);
}

// ---------------- GEMM1: h1[n,128] = x[n,128] @ W1[128,128] ----------------
__global__ __launch_bounds__(256) void k_gemm1(const float* __restrict__ x,
                                               const float* __restrict__ W,
                                               float* __restrict__ h, int n) {
    __shared__ float Wl[128 * 128];   // 64 KB
    __shared__ float xl[2][128];
    for (int i = threadIdx.x; i < 128 * 128; i += 256) Wl[i] = W[i];
    const int j  = threadIdx.x & 127;
    const int rs = threadIdx.x >> 7;  // 0..1
    const int base = blockIdx.x * 64;
    for (int r0 = 0; r0 < 64; r0 += 2) {
        const int row = base + r0 + rs;
        __syncthreads();  // also covers initial W staging
        xl[rs][j] = (row < n) ? x[row * 128 + j] : 0.0f;
        __syncthreads();
        if (row < n) {
            float acc = 0.0f;
#pragma unroll
            for (int k = 0; k < 128; ++k)
                acc = fmaf(xl[rs][k], Wl[k * 128 + j], acc);
            h[row * 128 + j] = acc;
        }
    }
}

// ---------------- layer-1 init: out1 = b1 + dinv^2 * h1 (self-loop) ----------------
__global__ void k_self1(const float* __restrict__ h, const float* __restrict__ dinv,
                        const float* __restrict__ b, float* __restrict__ out1, int n) {
    int i = blockIdx.x * blockDim.x + threadIdx.x;  // over n*128
    if (i < n * 128) {
        int row = i >> 7;
        float dv = dinv[row];
        out1[i] = fmaf(h[i], dv * dv, b[i & 127]);
    }
}

// ---------------- layer-1 scatter: out1[d] += norm * h1[s], 4 feats/thread ----------------
__global__ void k_scatter1(const float* __restrict__ h, const int* __restrict__ src,
                           const int* __restrict__ dst, const float* __restrict__ dinv,
                           float* __restrict__ out1, int e) {
    int gid = blockIdx.x * blockDim.x + threadIdx.x;  // over e*32
    if (gid >= e * 32) return;
    int eid = gid >> 5;
    int j4  = (gid & 31) << 2;
    int s = src[eid], d = dst[eid];
    float norm = dinv[s] * dinv[d];
    const float4 v = *reinterpret_cast<const float4*>(h + s * 128 + j4);
    float* o = out1 + d * 128 + j4;
    atomicAdd(o + 0, v.x * norm);
    atomicAdd(o + 1, v.y * norm);
    atomicAdd(o + 2, v.z * norm);
    atomicAdd(o + 3, v.w * norm);
}

// ---------------- GEMM2: h2[n,40] = relu(out1)[n,128] @ W2[128,40] ----------------
__global__ __launch_bounds__(256) void k_gemm2(const float* __restrict__ h1,
                                               const float* __restrict__ W,
                                               float* __restrict__ h2, int n) {
    __shared__ float Wl[128 * 40];    // 20 KB
    __shared__ float xl[4][128];
    for (int i = threadIdx.x; i < 128 * 40; i += 256) Wl[i] = W[i];
    const int j  = threadIdx.x & 63;
    const int rs = threadIdx.x >> 6;  // 0..3
    const int base = blockIdx.x * 64;
    for (int r0 = 0; r0 < 64; r0 += 4) {
        const int row = base + r0 + rs;
        __syncthreads();
        if (row < n) {
            xl[rs][j]      = fmaxf(h1[row * 128 + j], 0.0f);
            xl[rs][j + 64] = fmaxf(h1[row * 128 + j + 64], 0.0f);
        }
        __syncthreads();
        if (row < n && j < 40) {
            float acc = 0.0f;
#pragma unroll
            for (int k = 0; k < 128; ++k)
                acc = fmaf(xl[rs][k], Wl[k * 40 + j], acc);
            h2[row * 40 + j] = acc;
        }
    }
}

// ---------------- layer-2 init: out = b2 + dinv^2 * h2 (self-loop) ----------------
__global__ void k_self2(const float* __restrict__ h2, const float* __restrict__ dinv,
                        const float* __restrict__ b2, float* __restrict__ out, int n) {
    int i = blockIdx.x * blockDim.x + threadIdx.x;  // over n*40
    if (i < n * 40) {
        int row = i / 40;
        int j = i - row * 40;
        float dv = dinv[row];
        out[i] = fmaf(h2[i], dv * dv, b2[j]);
    }
}

// ---------------- layer-2 scatter ----------------
__global__ void k_scatter2(const float* __restrict__ h2, const int* __restrict__ src,
                           const int* __restrict__ dst, const float* __restrict__ dinv,
                           float* __restrict__ out, int e) {
    int gid = blockIdx.x * blockDim.x + threadIdx.x;  // over e*40
    if (gid >= e * 40) return;
    int eid = gid / 40;
    int j = gid - eid * 40;
    int s = src[eid], d = dst[eid];
    float norm = dinv[s] * dinv[d];
    atomicAdd(out + d * 40 + j, h2[s * 40 + j] * norm);
}

extern "C" void kernel_launch(void* const* d_in, const int* in_sizes, int n_in,
                              void* d_out, int out_size, void* d_ws, size_t ws_size,
                              hipStream_t stream) {
    const float* x  = (const float*)d_in[0];
    const int*   ei = (const int*)d_in[1];
    const float* W1 = (const float*)d_in[2];
    const float* b1 = (const float*)d_in[3];
    const float* W2 = (const float*)d_in[4];
    const float* b2 = (const float*)d_in[5];
    float* out = (float*)d_out;

    const int n = in_sizes[0] / 128;   // 50000
    const int e = in_sizes[1] / 2;     // 800000
    const int* src = ei;
    const int* dst = ei + e;

    // workspace layout (floats): dinv[n] | h1[n*128] (reused as h2[n*40]) | out1[n*128]
    float* ws   = (float*)d_ws;
    float* dinv = ws;
    float* h1   = ws + ((n + 63) / 64) * 64;
    float* out1 = h1 + (size_t)n * 128;
    float* h2   = h1;  // gemm2 reads out1, so h1's region is free by then

    const int nb_n    = (n + THREADS - 1) / THREADS;
    const int nb_e    = (e + THREADS - 1) / THREADS;
    const int nb_rows = (n + 63) / 64;

    k_deg_init<<<nb_n, THREADS, 0, stream>>>(dinv, n);
    k_deg_acc<<<nb_e, THREADS, 0, stream>>>(dst, dinv, e);
    k_rsqrt<<<nb_n, THREADS, 0, stream>>>(dinv, n);

    k_gemm1<<<nb_rows, THREADS, 0, stream>>>(x, W1, h1, n);
    k_self1<<<(n * 128 + THREADS - 1) / THREADS, THREADS, 0, stream>>>(h1, dinv, b1, out1, n);
    k_scatter1<<<(e * 32 + THREADS - 1) / THREADS, THREADS, 0, stream>>>(h1, src, dst, dinv, out1, e);

    k_gemm2<<<nb_rows, THREADS, 0, stream>>>(out1, W2, h2, n);
    k_self2<<<(n * 40 + THREADS - 1) / THREADS, THREADS, 0, stream>>>(h2, dinv, b2, out, n);
    k_scatter2<<<(e * 40 + THREADS - 1) / THREADS, THREADS, 0, stream>>>(h2, src, dst, dinv, out, e);
}

// Round 2
// 381.872 us; speedup vs baseline: 4.4728x; 4.4728x over previous
//
#include <hip/hip_runtime.h>

#define THREADS 256
#define SCAN_CHUNK 2048   // 256 threads x 8 elems

// ---------------- CSR build ----------------
__global__ void k_zero(int* __restrict__ counts, int n) {
    int i = blockIdx.x * blockDim.x + threadIdx.x;
    if (i < n) counts[i] = 0;
}

__global__ void k_count(const int* __restrict__ dst, int* __restrict__ counts, int e) {
    int i = blockIdx.x * blockDim.x + threadIdx.x;
    if (i < e) atomicAdd(&counts[dst[i]], 1);
}

__global__ void k_dinv(const int* __restrict__ counts, float* __restrict__ dinv, int n) {
    int i = blockIdx.x * blockDim.x + threadIdx.x;
    if (i < n) dinv[i] = rsqrtf((float)(counts[i] + 1));  // +1 self-loop
}

// inclusive scan of counts within 2048-chunks -> rowptr[i+1]; chunk totals -> bsum[b]
__global__ __launch_bounds__(256) void k_scan1(const int* __restrict__ counts,
                                               int* __restrict__ rowptr,
                                               int* __restrict__ bsum, int n) {
    __shared__ int s[256];
    const int t = threadIdx.x;
    const int base = blockIdx.x * SCAN_CHUNK + t * 8;
    int c[8];
    int run = 0;
#pragma unroll
    for (int k = 0; k < 8; ++k) {
        int i = base + k;
        c[k] = (i < n) ? counts[i] : 0;
        run += c[k];
        c[k] = run;  // running inclusive within thread
    }
    s[t] = run;
    __syncthreads();
    for (int off = 1; off < 256; off <<= 1) {
        int v = (t >= off) ? s[t - off] : 0;
        __syncthreads();
        s[t] += v;
        __syncthreads();
    }
    const int excl = s[t] - run;  // exclusive offset for this thread
#pragma unroll
    for (int k = 0; k < 8; ++k) {
        int i = base + k;
        if (i < n) rowptr[i + 1] = c[k] + excl;
    }
    if (t == 255) bsum[blockIdx.x] = s[255];
}

// exclusive scan of block sums (nb <= 256)
__global__ __launch_bounds__(256) void k_scan2(int* __restrict__ bsum, int nb) {
    __shared__ int s[256];
    const int t = threadIdx.x;
    int v0 = (t < nb) ? bsum[t] : 0;
    s[t] = v0;
    __syncthreads();
    for (int off = 1; off < 256; off <<= 1) {
        int v = (t >= off) ? s[t - off] : 0;
        __syncthreads();
        s[t] += v;
        __syncthreads();
    }
    if (t < nb) bsum[t] = s[t] - v0;  // exclusive
}

// add chunk offsets; produce fillptr[i] = rowptr[i] (start of bucket i)
__global__ __launch_bounds__(256) void k_scan3(const int* __restrict__ counts,
                                               int* __restrict__ rowptr,
                                               int* __restrict__ fillptr,
                                               const int* __restrict__ bsum, int n) {
    const int off = bsum[blockIdx.x];
    const int t = threadIdx.x;
#pragma unroll
    for (int k = 0; k < 8; ++k) {
        int i = blockIdx.x * SCAN_CHUNK + t + k * 256;
        if (i < n) {
            int incl = rowptr[i + 1] + off;
            rowptr[i + 1] = incl;
            fillptr[i] = incl - counts[i];
        }
    }
    if (blockIdx.x == 0 && t == 0) rowptr[0] = 0;
}

__global__ void k_fill(const int* __restrict__ src, const int* __restrict__ dst,
                       int* __restrict__ fillptr, int* __restrict__ csr_src, int e) {
    int i = blockIdx.x * blockDim.x + threadIdx.x;
    if (i < e) {
        int pos = atomicAdd(&fillptr[dst[i]], 1);
        csr_src[pos] = src[i];
    }
}

// ---------------- GEMM1: h1[n,128] = x[n,128] @ W1[128,128] ----------------
__global__ __launch_bounds__(256) void k_gemm1(const float* __restrict__ x,
                                               const float* __restrict__ W,
                                               float* __restrict__ h, int n) {
    __shared__ float Wl[128 * 128];   // 64 KB
    __shared__ float xl[2][128];
    for (int i = threadIdx.x; i < 128 * 128; i += 256) Wl[i] = W[i];
    const int j  = threadIdx.x & 127;
    const int rs = threadIdx.x >> 7;  // 0..1
    const int base = blockIdx.x * 64;
    for (int r0 = 0; r0 < 64; r0 += 2) {
        const int row = base + r0 + rs;
        __syncthreads();
        xl[rs][j] = (row < n) ? x[row * 128 + j] : 0.0f;
        __syncthreads();
        if (row < n) {
            float acc = 0.0f;
#pragma unroll
            for (int k = 0; k < 128; ++k)
                acc = fmaf(xl[rs][k], Wl[k * 128 + j], acc);
            h[row * 128 + j] = acc;
        }
    }
}

// ---------------- gather1: out1[d] = b1 + dinv[d]*(dinv[d]*h1[d] + sum dinv[s]*h1[s]) ----------------
__global__ __launch_bounds__(64) void k_gather1(const float* __restrict__ h1,
                                                const int* __restrict__ rowptr,
                                                const int* __restrict__ csr_src,
                                                const float* __restrict__ dinv,
                                                const float* __restrict__ b1,
                                                float* __restrict__ out1, int n) {
    const int d = blockIdx.x;
    if (d >= n) return;
    const int j2 = threadIdx.x * 2;
    const float dd = dinv[d];
    const float2 self = *reinterpret_cast<const float2*>(h1 + (size_t)d * 128 + j2);
    float accx = dd * self.x, accy = dd * self.y;
    const int beg = rowptr[d], end = rowptr[d + 1];
    for (int p = beg; p < end; ++p) {
        const int s = csr_src[p];
        const float w = dinv[s];
        const float2 v = *reinterpret_cast<const float2*>(h1 + (size_t)s * 128 + j2);
        accx = fmaf(w, v.x, accx);
        accy = fmaf(w, v.y, accy);
    }
    const float2 bb = *reinterpret_cast<const float2*>(b1 + j2);
    float2 r;
    r.x = fmaf(dd, accx, bb.x);
    r.y = fmaf(dd, accy, bb.y);
    *reinterpret_cast<float2*>(out1 + (size_t)d * 128 + j2) = r;
}

// ---------------- GEMM2: h2[n,40] = relu(out1)[n,128] @ W2[128,40] ----------------
__global__ __launch_bounds__(256) void k_gemm2(const float* __restrict__ h1,
                                               const float* __restrict__ W,
                                               float* __restrict__ h2, int n) {
    __shared__ float Wl[128 * 40];    // 20 KB
    __shared__ float xl[4][128];
    for (int i = threadIdx.x; i < 128 * 40; i += 256) Wl[i] = W[i];
    const int j  = threadIdx.x & 63;
    const int rs = threadIdx.x >> 6;  // 0..3
    const int base = blockIdx.x * 64;
    for (int r0 = 0; r0 < 64; r0 += 4) {
        const int row = base + r0 + rs;
        __syncthreads();
        if (row < n) {
            xl[rs][j]      = fmaxf(h1[row * 128 + j], 0.0f);
            xl[rs][j + 64] = fmaxf(h1[row * 128 + j + 64], 0.0f);
        }
        __syncthreads();
        if (row < n && j < 40) {
            float acc = 0.0f;
#pragma unroll
            for (int k = 0; k < 128; ++k)
                acc = fmaf(xl[rs][k], Wl[k * 40 + j], acc);
            h2[row * 40 + j] = acc;
        }
    }
}

// ---------------- gather2: out[d] = b2 + dinv[d]*(dinv[d]*h2[d] + sum dinv[s]*h2[s]) ----------------
__global__ __launch_bounds__(64) void k_gather2(const float* __restrict__ h2,
                                                const int* __restrict__ rowptr,
                                                const int* __restrict__ csr_src,
                                                const float* __restrict__ dinv,
                                                const float* __restrict__ b2,
                                                float* __restrict__ out, int n) {
    const int d = blockIdx.x;
    if (d >= n) return;
    const int j = threadIdx.x;
    if (j >= 40) return;
    const float dd = dinv[d];
    float acc = dd * h2[(size_t)d * 40 + j];
    const int beg = rowptr[d], end = rowptr[d + 1];
    for (int p = beg; p < end; ++p) {
        const int s = csr_src[p];
        acc = fmaf(dinv[s], h2[(size_t)s * 40 + j], acc);
    }
    out[(size_t)d * 40 + j] = fmaf(dd, acc, b2[j]);
}

extern "C" void kernel_launch(void* const* d_in, const int* in_sizes, int n_in,
                              void* d_out, int out_size, void* d_ws, size_t ws_size,
                              hipStream_t stream) {
    const float* x  = (const float*)d_in[0];
    const int*   ei = (const int*)d_in[1];
    const float* b1 = (const float*)d_in[3];
    const float* W1 = (const float*)d_in[2];
    const float* W2 = (const float*)d_in[4];
    const float* b2 = (const float*)d_in[5];
    float* out = (float*)d_out;

    const int n = in_sizes[0] / 128;   // 50000
    const int e = in_sizes[1] / 2;     // 800000
    const int* src = ei;
    const int* dst = ei + e;

    const int n_pad = ((n + 63) / 64) * 64;
    const int e_pad = ((e + 63) / 64) * 64;

    // ws layout (4B units):
    //   dinv[n_pad] | rowptr[n_pad+64] | csr_src[e_pad] | h1[n*128] | out1[n*128]
    // counts/fillptr/bsum overlay the h1 region (dead before k_gemm1 writes h1);
    // h2 overlays h1 (h1 dead after k_gather1).
    float* ws      = (float*)d_ws;
    float* dinv    = ws;
    int*   rowptr  = (int*)(ws + n_pad);
    int*   csr_src = rowptr + n_pad + 64;
    float* h1      = (float*)(csr_src + e_pad);
    float* out1    = h1 + (size_t)n * 128;
    int*   counts  = (int*)h1;          // overlay
    int*   fillptr = counts + n_pad;    // overlay
    int*   bsum    = fillptr + n_pad;   // overlay
    float* h2      = h1;                // overlay

    const int nb_n    = (n + THREADS - 1) / THREADS;
    const int nb_e    = (e + THREADS - 1) / THREADS;
    const int nb_scan = (n + SCAN_CHUNK - 1) / SCAN_CHUNK;
    const int nb_rows = (n + 63) / 64;

    // CSR build
    k_zero <<<nb_n, THREADS, 0, stream>>>(counts, n);
    k_count<<<nb_e, THREADS, 0, stream>>>(dst, counts, e);
    k_dinv <<<nb_n, THREADS, 0, stream>>>(counts, dinv, n);
    k_scan1<<<nb_scan, 256, 0, stream>>>(counts, rowptr, bsum, n);
    k_scan2<<<1, 256, 0, stream>>>(bsum, nb_scan);
    k_scan3<<<nb_scan, 256, 0, stream>>>(counts, rowptr, fillptr, bsum, n);
    k_fill <<<nb_e, THREADS, 0, stream>>>(src, dst, fillptr, csr_src, e);

    // layer 1
    k_gemm1  <<<nb_rows, 256, 0, stream>>>(x, W1, h1, n);
    k_gather1<<<n, 64, 0, stream>>>(h1, rowptr, csr_src, dinv, b1, out1, n);

    // layer 2
    k_gemm2  <<<nb_rows, 256, 0, stream>>>(out1, W2, h2, n);
    k_gather2<<<n, 64, 0, stream>>>(h2, rowptr, csr_src, dinv, b2, out, n);
}

// Round 3
// 269.161 us; speedup vs baseline: 6.3458x; 1.4188x over previous
//
#include <hip/hip_runtime.h>

#define THREADS 256
#define SCAN_CHUNK 2048   // 256 threads x 8 elems

// ---------------- CSR build ----------------
__global__ void k_zero(int* __restrict__ counts, int n) {
    int i = blockIdx.x * blockDim.x + threadIdx.x;
    if (i < n) counts[i] = 0;
}

__global__ void k_count(const int* __restrict__ dst, int* __restrict__ counts, int e) {
    int i = blockIdx.x * blockDim.x + threadIdx.x;
    if (i < e) atomicAdd(&counts[dst[i]], 1);
}

__global__ void k_dinv(const int* __restrict__ counts, float* __restrict__ dinv, int n) {
    int i = blockIdx.x * blockDim.x + threadIdx.x;
    if (i < n) dinv[i] = rsqrtf((float)(counts[i] + 1));  // +1 self-loop
}

// inclusive scan of counts within 2048-chunks -> rowptr[i+1]; chunk totals -> bsum[b]
__global__ __launch_bounds__(256) void k_scan1(const int* __restrict__ counts,
                                               int* __restrict__ rowptr,
                                               int* __restrict__ bsum, int n) {
    __shared__ int s[256];
    const int t = threadIdx.x;
    const int base = blockIdx.x * SCAN_CHUNK + t * 8;
    int c[8];
    int run = 0;
#pragma unroll
    for (int k = 0; k < 8; ++k) {
        int i = base + k;
        c[k] = (i < n) ? counts[i] : 0;
        run += c[k];
        c[k] = run;  // running inclusive within thread
    }
    s[t] = run;
    __syncthreads();
    for (int off = 1; off < 256; off <<= 1) {
        int v = (t >= off) ? s[t - off] : 0;
        __syncthreads();
        s[t] += v;
        __syncthreads();
    }
    const int excl = s[t] - run;  // exclusive offset for this thread
#pragma unroll
    for (int k = 0; k < 8; ++k) {
        int i = base + k;
        if (i < n) rowptr[i + 1] = c[k] + excl;
    }
    if (t == 255) bsum[blockIdx.x] = s[255];
}

// exclusive scan of block sums (nb <= 256)
__global__ __launch_bounds__(256) void k_scan2(int* __restrict__ bsum, int nb) {
    __shared__ int s[256];
    const int t = threadIdx.x;
    int v0 = (t < nb) ? bsum[t] : 0;
    s[t] = v0;
    __syncthreads();
    for (int off = 1; off < 256; off <<= 1) {
        int v = (t >= off) ? s[t - off] : 0;
        __syncthreads();
        s[t] += v;
        __syncthreads();
    }
    if (t < nb) bsum[t] = s[t] - v0;  // exclusive
}

// add chunk offsets; produce fillptr[i] = rowptr[i] (start of bucket i)
__global__ __launch_bounds__(256) void k_scan3(const int* __restrict__ counts,
                                               int* __restrict__ rowptr,
                                               int* __restrict__ fillptr,
                                               const int* __restrict__ bsum, int n) {
    const int off = bsum[blockIdx.x];
    const int t = threadIdx.x;
#pragma unroll
    for (int k = 0; k < 8; ++k) {
        int i = blockIdx.x * SCAN_CHUNK + t + k * 256;
        if (i < n) {
            int incl = rowptr[i + 1] + off;
            rowptr[i + 1] = incl;
            fillptr[i] = incl - counts[i];
        }
    }
    if (blockIdx.x == 0 && t == 0) rowptr[0] = 0;
}

__global__ void k_fill(const int* __restrict__ src, const int* __restrict__ dst,
                       int* __restrict__ fillptr, int* __restrict__ csr_src, int e) {
    int i = blockIdx.x * blockDim.x + threadIdx.x;
    if (i < e) {
        int pos = atomicAdd(&fillptr[dst[i]], 1);
        csr_src[pos] = src[i];
    }
}

// ---------------- GEMM1: h1[n,128] = x[n,128] @ W1[128,128] ----------------
// 64 rows/block, 256 thr; thread = (colgroup cg=t&31 -> cols 4cg..4cg+3,
// rowgroup rg=t>>5 -> rows 8rg..8rg+7); K staged in two 64-halves.
__global__ __launch_bounds__(256) void k_gemm1(const float* __restrict__ x,
                                               const float* __restrict__ W,
                                               float* __restrict__ h, int n) {
    __shared__ float Wl[64 * 128];  // 32 KB, [kk][j]
    __shared__ float xl[64 * 64];   // 16 KB, [r][kk]
    const int t  = threadIdx.x;
    const int cg = t & 31;
    const int rg = t >> 5;
    const int base = blockIdx.x * 64;

    float acc[8][4];
#pragma unroll
    for (int i = 0; i < 8; ++i)
#pragma unroll
        for (int j = 0; j < 4; ++j) acc[i][j] = 0.0f;

    for (int ph = 0; ph < 2; ++ph) {
        __syncthreads();
        // stage W K-half: 8192 floats = 2048 float4, 8/thread (coalesced)
        {
            const float4* Wg = (const float4*)(W + ph * 64 * 128);
            float4* Ws = (float4*)Wl;
#pragma unroll
            for (int i = 0; i < 8; ++i) Ws[t + 256 * i] = Wg[t + 256 * i];
        }
        // stage x K-half: 64 rows x 16 float4, 4/thread
#pragma unroll
        for (int i = 0; i < 4; ++i) {
            const int idx = t + 256 * i;
            const int r = idx >> 4, c4 = idx & 15;
            const int row = base + r;
            float4 v = make_float4(0.f, 0.f, 0.f, 0.f);
            if (row < n) v = *(const float4*)(x + (size_t)row * 128 + ph * 64 + c4 * 4);
            *(float4*)(xl + r * 64 + c4 * 4) = v;
        }
        __syncthreads();

        for (int k4 = 0; k4 < 16; ++k4) {
            float wv[4][4];
#pragma unroll
            for (int kk = 0; kk < 4; ++kk) {
                const float4 w4 = *(const float4*)(Wl + (k4 * 4 + kk) * 128 + cg * 4);
                wv[kk][0] = w4.x; wv[kk][1] = w4.y; wv[kk][2] = w4.z; wv[kk][3] = w4.w;
            }
#pragma unroll
            for (int i = 0; i < 8; ++i) {
                const float4 x4 = *(const float4*)(xl + (rg * 8 + i) * 64 + k4 * 4);
                const float xs[4] = {x4.x, x4.y, x4.z, x4.w};
#pragma unroll
                for (int kk = 0; kk < 4; ++kk)
#pragma unroll
                    for (int j = 0; j < 4; ++j)
                        acc[i][j] = fmaf(xs[kk], wv[kk][j], acc[i][j]);
            }
        }
    }

#pragma unroll
    for (int i = 0; i < 8; ++i) {
        const int row = base + rg * 8 + i;
        if (row < n) {
            float4 r4 = make_float4(acc[i][0], acc[i][1], acc[i][2], acc[i][3]);
            *(float4*)(h + (size_t)row * 128 + cg * 4) = r4;
        }
    }
}

// ---------------- gather1: out1[d] = b1 + dinv[d]*(dinv[d]*h1[d] + sum dinv[s]*h1[s]) ----------------
__global__ __launch_bounds__(64) void k_gather1(const float* __restrict__ h1,
                                                const int* __restrict__ rowptr,
                                                const int* __restrict__ csr_src,
                                                const float* __restrict__ dinv,
                                                const float* __restrict__ b1,
                                                float* __restrict__ out1, int n) {
    const int d = blockIdx.x;
    if (d >= n) return;
    const int j2 = threadIdx.x * 2;
    const float dd = dinv[d];
    const float2 self = *reinterpret_cast<const float2*>(h1 + (size_t)d * 128 + j2);
    float accx = dd * self.x, accy = dd * self.y;
    const int beg = rowptr[d], end = rowptr[d + 1];
    for (int p = beg; p < end; ++p) {
        const int s = csr_src[p];
        const float w = dinv[s];
        const float2 v = *reinterpret_cast<const float2*>(h1 + (size_t)s * 128 + j2);
        accx = fmaf(w, v.x, accx);
        accy = fmaf(w, v.y, accy);
    }
    const float2 bb = *reinterpret_cast<const float2*>(b1 + j2);
    float2 r;
    r.x = fmaf(dd, accx, bb.x);
    r.y = fmaf(dd, accy, bb.y);
    *reinterpret_cast<float2*>(out1 + (size_t)d * 128 + j2) = r;
}

// ---------------- GEMM2: h2[n,40] = relu(out1)[n,128] @ W2[128,40] ----------------
// cols padded to 64 (zeros in LDS); 64 rows/block; thread = (cg=t&15 -> cols 4cg,
// rg=t>>4 -> rows 4rg..4rg+3); K in two 64-halves; relu fused into x staging.
__global__ __launch_bounds__(256) void k_gemm2(const float* __restrict__ h1,
                                               const float* __restrict__ W,
                                               float* __restrict__ h2, int n) {
    __shared__ float Wl[64 * 64];   // 16 KB, [kk][j] zero-padded j>=40
    __shared__ float xl[64 * 64];   // 16 KB, [r][kk]
    const int t  = threadIdx.x;
    const int cg = t & 15;
    const int rg = t >> 4;
    const int base = blockIdx.x * 64;

    float acc[4][4];
#pragma unroll
    for (int i = 0; i < 4; ++i)
#pragma unroll
        for (int j = 0; j < 4; ++j) acc[i][j] = 0.0f;

    for (int ph = 0; ph < 2; ++ph) {
        __syncthreads();
        // stage W K-half with zero pad: 64x64, 16 scalars/thread
#pragma unroll
        for (int i = 0; i < 16; ++i) {
            const int idx = t + 256 * i;
            const int r = idx >> 6, c = idx & 63;
            Wl[idx] = (c < 40) ? W[(ph * 64 + r) * 40 + c] : 0.0f;
        }
        // stage relu(h1) K-half: 64 rows x 16 float4, 4/thread
#pragma unroll
        for (int i = 0; i < 4; ++i) {
            const int idx = t + 256 * i;
            const int r = idx >> 4, c4 = idx & 15;
            const int row = base + r;
            float4 v = make_float4(0.f, 0.f, 0.f, 0.f);
            if (row < n) {
                v = *(const float4*)(h1 + (size_t)row * 128 + ph * 64 + c4 * 4);
                v.x = fmaxf(v.x, 0.f); v.y = fmaxf(v.y, 0.f);
                v.z = fmaxf(v.z, 0.f); v.w = fmaxf(v.w, 0.f);
            }
            *(float4*)(xl + r * 64 + c4 * 4) = v;
        }
        __syncthreads();

        for (int k4 = 0; k4 < 16; ++k4) {
            float wv[4][4];
#pragma unroll
            for (int kk = 0; kk < 4; ++kk) {
                const float4 w4 = *(const float4*)(Wl + (k4 * 4 + kk) * 64 + cg * 4);
                wv[kk][0] = w4.x; wv[kk][1] = w4.y; wv[kk][2] = w4.z; wv[kk][3] = w4.w;
            }
#pragma unroll
            for (int i = 0; i < 4; ++i) {
                const float4 x4 = *(const float4*)(xl + (rg * 4 + i) * 64 + k4 * 4);
                const float xs[4] = {x4.x, x4.y, x4.z, x4.w};
#pragma unroll
                for (int kk = 0; kk < 4; ++kk)
#pragma unroll
                    for (int j = 0; j < 4; ++j)
                        acc[i][j] = fmaf(xs[kk], wv[kk][j], acc[i][j]);
            }
        }
    }

    if (cg < 10) {  // cols 4cg..4cg+3 < 40
#pragma unroll
        for (int i = 0; i < 4; ++i) {
            const int row = base + rg * 4 + i;
            if (row < n) {
                float4 r4 = make_float4(acc[i][0], acc[i][1], acc[i][2], acc[i][3]);
                *(float4*)(h2 + (size_t)row * 40 + cg * 4) = r4;
            }
        }
    }
}

// ---------------- gather2: out[d] = b2 + dinv[d]*(dinv[d]*h2[d] + sum dinv[s]*h2[s]) ----------------
__global__ __launch_bounds__(64) void k_gather2(const float* __restrict__ h2,
                                                const int* __restrict__ rowptr,
                                                const int* __restrict__ csr_src,
                                                const float* __restrict__ dinv,
                                                const float* __restrict__ b2,
                                                float* __restrict__ out, int n) {
    const int d = blockIdx.x;
    if (d >= n) return;
    const int j = threadIdx.x;
    if (j >= 40) return;
    const float dd = dinv[d];
    float acc = dd * h2[(size_t)d * 40 + j];
    const int beg = rowptr[d], end = rowptr[d + 1];
    for (int p = beg; p < end; ++p) {
        const int s = csr_src[p];
        acc = fmaf(dinv[s], h2[(size_t)s * 40 + j], acc);
    }
    out[(size_t)d * 40 + j] = fmaf(dd, acc, b2[j]);
}

extern "C" void kernel_launch(void* const* d_in, const int* in_sizes, int n_in,
                              void* d_out, int out_size, void* d_ws, size_t ws_size,
                              hipStream_t stream) {
    const float* x  = (const float*)d_in[0];
    const int*   ei = (const int*)d_in[1];
    const float* W1 = (const float*)d_in[2];
    const float* b1 = (const float*)d_in[3];
    const float* W2 = (const float*)d_in[4];
    const float* b2 = (const float*)d_in[5];
    float* out = (float*)d_out;

    const int n = in_sizes[0] / 128;   // 50000
    const int e = in_sizes[1] / 2;     // 800000
    const int* src = ei;
    const int* dst = ei + e;

    const int n_pad = ((n + 63) / 64) * 64;
    const int e_pad = ((e + 63) / 64) * 64;

    // ws layout (4B units):
    //   dinv[n_pad] | rowptr[n_pad+64] | csr_src[e_pad] | h1[n*128] | out1[n*128]
    // counts/fillptr/bsum overlay the h1 region (dead before k_gemm1 writes h1);
    // h2 overlays h1 (h1 dead after k_gather1).
    float* ws      = (float*)d_ws;
    float* dinv    = ws;
    int*   rowptr  = (int*)(ws + n_pad);
    int*   csr_src = rowptr + n_pad + 64;
    float* h1      = (float*)(csr_src + e_pad);
    float* out1    = h1 + (size_t)n * 128;
    int*   counts  = (int*)h1;          // overlay
    int*   fillptr = counts + n_pad;    // overlay
    int*   bsum    = fillptr + n_pad;   // overlay
    float* h2      = h1;                // overlay

    const int nb_n    = (n + THREADS - 1) / THREADS;
    const int nb_e    = (e + THREADS - 1) / THREADS;
    const int nb_scan = (n + SCAN_CHUNK - 1) / SCAN_CHUNK;
    const int nb_rows = (n + 63) / 64;

    // CSR build
    k_zero <<<nb_n, THREADS, 0, stream>>>(counts, n);
    k_count<<<nb_e, THREADS, 0, stream>>>(dst, counts, e);
    k_dinv <<<nb_n, THREADS, 0, stream>>>(counts, dinv, n);
    k_scan1<<<nb_scan, 256, 0, stream>>>(counts, rowptr, bsum, n);
    k_scan2<<<1, 256, 0, stream>>>(bsum, nb_scan);
    k_scan3<<<nb_scan, 256, 0, stream>>>(counts, rowptr, fillptr, bsum, n);
    k_fill <<<nb_e, THREADS, 0, stream>>>(src, dst, fillptr, csr_src, e);

    // layer 1
    k_gemm1  <<<nb_rows, 256, 0, stream>>>(x, W1, h1, n);
    k_gather1<<<n, 64, 0, stream>>>(h1, rowptr, csr_src, dinv, b1, out1, n);

    // layer 2
    k_gemm2  <<<nb_rows, 256, 0, stream>>>(out1, W2, h2, n);
    k_gather2<<<n, 64, 0, stream>>>(h2, rowptr, csr_src, dinv, b2, out, n);
}